// Round 1
// baseline (441.397 us; speedup 1.0000x reference)
//
#include <hip/hip_runtime.h>

// LSTM: B=4096 (from in_sizes), T=1024, I=8, H=4 fixed by the module.
// Layout: 4 lanes per batch element (lane j of an aligned quad owns h_j, c_j
// and gate rows {j, 4+j, 8+j, 12+j}). Cross-lane h-broadcast via DPP
// quad_perm (VALU pipe) — avoids ds_bpermute's ~100cyc LDS latency on the
// serial chain. 1 thread-block of 64 per wave, 16 batch elems per wave.

#define TT 1024
#define II 8

template <int CTRL>
__device__ __forceinline__ float dppf(float v) {
  return __int_as_float(
      __builtin_amdgcn_mov_dpp(__float_as_int(v), CTRL, 0xF, 0xF, true));
}

__device__ __forceinline__ float fast_sigmoid(float x) {
  // 1/(1+e^-x); v_exp + v_rcp, ~1 ulp each — fine vs 1.4e-2 threshold
  return __builtin_amdgcn_rcpf(1.0f + __expf(-x));
}

__device__ __forceinline__ float fast_tanh(float x) {
  // tanh = 1 - 2/(e^{2x}+1); overflow -> inf -> rcp=0 -> 1 (graceful)
  return 1.0f - 2.0f * __builtin_amdgcn_rcpf(__expf(2.0f * x) + 1.0f);
}

__global__ __launch_bounds__(64, 1) void lstm_fused(
    const float* __restrict__ x, const float* __restrict__ W_ih,
    const float* __restrict__ W_hh, const float* __restrict__ b_ih,
    const float* __restrict__ b_hh, const float* __restrict__ fc_w,
    const float* __restrict__ fc_b, float* __restrict__ out, int B) {
  const int lane = threadIdx.x;  // 0..63, full wave
  const int j = lane & 3;        // owned hidden index
  const int grp = lane >> 2;     // 0..15: batch group within wave
  int b = blockIdx.x * 16 + grp;
  const int bb = (b < B) ? b : (B - 1);  // clamp for safe loads

  // Per-lane weights: 4 gate rows (i,f,g,o for hidden j)
  float wih[4][II];
  float whh[4][4];
  float bias[4];
#pragma unroll
  for (int r4 = 0; r4 < 4; ++r4) {
    const int r = r4 * 4 + j;  // PyTorch gate order: i=0..3, f=4..7, g=8..11, o=12..15
#pragma unroll
    for (int k = 0; k < II; ++k) wih[r4][k] = W_ih[r * II + k];
#pragma unroll
    for (int k = 0; k < 4; ++k) whh[r4][k] = W_hh[r * 4 + k];
    bias[r4] = b_ih[r] + b_hh[r];
  }

  const float4* __restrict__ xp = (const float4*)(x + (size_t)bb * TT * II);

  float h = 0.0f, c = 0.0f;
  // software-pipelined x_t (8 floats = 2 x float4, same addr across the quad
  // -> L1 broadcast; streams are contiguous per batch elem)
  float4 xa = xp[0];
  float4 xb = xp[1];

  for (int t = 0; t < TT; ++t) {
    const int tn = (t + 1 < TT) ? (t + 1) : t;  // clamp: harmless reload at tail
    const float4 na = xp[2 * tn];
    const float4 nb = xp[2 * tn + 1];

    // --- x-projection (off the serial critical path) ---
    float acc[4];
#pragma unroll
    for (int r4 = 0; r4 < 4; ++r4) {
      float a = bias[r4];
      a = fmaf(wih[r4][0], xa.x, a);
      a = fmaf(wih[r4][1], xa.y, a);
      a = fmaf(wih[r4][2], xa.z, a);
      a = fmaf(wih[r4][3], xa.w, a);
      a = fmaf(wih[r4][4], xb.x, a);
      a = fmaf(wih[r4][5], xb.y, a);
      a = fmaf(wih[r4][6], xb.z, a);
      a = fmaf(wih[r4][7], xb.w, a);
      acc[r4] = a;
    }

    // --- serial part: broadcast h0..h3 within the quad (DPP, VALU pipe) ---
    const float h0 = dppf<0x00>(h);
    const float h1 = dppf<0x55>(h);
    const float h2 = dppf<0xAA>(h);
    const float h3 = dppf<0xFF>(h);
#pragma unroll
    for (int r4 = 0; r4 < 4; ++r4) {
      float a = acc[r4];
      a = fmaf(whh[r4][0], h0, a);
      a = fmaf(whh[r4][1], h1, a);
      a = fmaf(whh[r4][2], h2, a);
      a = fmaf(whh[r4][3], h3, a);
      acc[r4] = a;
    }

    const float ig = fast_sigmoid(acc[0]);
    const float fg = fast_sigmoid(acc[1]);
    const float gg = fast_tanh(acc[2]);
    const float og = fast_sigmoid(acc[3]);
    c = fmaf(fg, c, ig * gg);
    h = og * fast_tanh(c);

    xa = na;
    xb = nb;
  }

  // --- final FC: out[b] = sum_j h_j * fc_w[j] + fc_b ---
  float v = h * fc_w[j];
  v += dppf<0xB1>(v);  // quad_perm [1,0,3,2]: xor 1
  v += dppf<0x4E>(v);  // quad_perm [2,3,0,1]: xor 2
  if (j == 0 && b < B) out[b] = v + fc_b[0];
}

extern "C" void kernel_launch(void* const* d_in, const int* in_sizes, int n_in,
                              void* d_out, int out_size, void* d_ws,
                              size_t ws_size, hipStream_t stream) {
  const float* x = (const float*)d_in[0];
  const float* W_ih = (const float*)d_in[1];
  const float* W_hh = (const float*)d_in[2];
  const float* b_ih = (const float*)d_in[3];
  const float* b_hh = (const float*)d_in[4];
  const float* fc_w = (const float*)d_in[5];
  const float* fc_b = (const float*)d_in[6];
  float* out = (float*)d_out;

  const int B = in_sizes[0] / (TT * II);
  const int nblocks = (B + 15) / 16;
  lstm_fused<<<nblocks, 64, 0, stream>>>(x, W_ih, W_hh, b_ih, b_hh, fc_w, fc_b,
                                         out, B);
}

// Round 2
// 413.195 us; speedup vs baseline: 1.0683x; 1.0683x over previous
//
#include <hip/hip_runtime.h>

// LSTM: B=4096, T=1024, I=8, H=4. fp32.
// Layout: 4 lanes per batch element (lane j of an aligned quad owns h_j, c_j
// and gate rows {j, 4+j, 8+j, 12+j}). Cross-lane h-broadcast via DPP
// quad_perm (VALU pipe, stays off the LDS pipe).
// R2: 8-step-deep register prefetch (unroll x8, circular float4 buffer).
// R1 showed 698 cyc/step = ~150 compute + ~550 HBM-latency stall with only
// 1 wave/CU; 16 outstanding loads issued 8 steps ahead hide the ~900cyc miss.

#define TT 1024
#define II 8
#define DEPTH 8  // prefetch depth in steps; 8*150cyc > 900cyc HBM latency

template <int CTRL>
__device__ __forceinline__ float dppf(float v) {
  return __int_as_float(
      __builtin_amdgcn_mov_dpp(__float_as_int(v), CTRL, 0xF, 0xF, true));
}

__device__ __forceinline__ float fast_sigmoid(float x) {
  return __builtin_amdgcn_rcpf(1.0f + __expf(-x));
}

__device__ __forceinline__ float fast_tanh(float x) {
  // tanh = 1 - 2/(e^{2x}+1); overflow -> inf -> rcp=0 -> 1 (graceful)
  return 1.0f - 2.0f * __builtin_amdgcn_rcpf(__expf(2.0f * x) + 1.0f);
}

__global__ __launch_bounds__(64, 1) void lstm_fused(
    const float* __restrict__ x, const float* __restrict__ W_ih,
    const float* __restrict__ W_hh, const float* __restrict__ b_ih,
    const float* __restrict__ b_hh, const float* __restrict__ fc_w,
    const float* __restrict__ fc_b, float* __restrict__ out, int B) {
  const int lane = threadIdx.x;  // 0..63
  const int j = lane & 3;        // owned hidden index
  const int grp = lane >> 2;     // batch group within wave
  int b = blockIdx.x * 16 + grp;
  const int bb = (b < B) ? b : (B - 1);

  // Per-lane weights: 4 gate rows (i,f,g,o for hidden j), PyTorch order.
  float wih[4][II];
  float whh[4][4];
  float bias[4];
#pragma unroll
  for (int r4 = 0; r4 < 4; ++r4) {
    const int r = r4 * 4 + j;
#pragma unroll
    for (int k = 0; k < II; ++k) wih[r4][k] = W_ih[r * II + k];
#pragma unroll
    for (int k = 0; k < 4; ++k) whh[r4][k] = W_hh[r * 4 + k];
    bias[r4] = b_ih[r] + b_hh[r];
  }

  const float4* __restrict__ xp = (const float4*)(x + (size_t)bb * TT * II);

  // Prime the 8-step circular register buffer.
  float4 buf[DEPTH][2];
#pragma unroll
  for (int u = 0; u < DEPTH; ++u) {
    buf[u][0] = xp[2 * u];
    buf[u][1] = xp[2 * u + 1];
  }

  float h = 0.0f, c = 0.0f;

  for (int t0 = 0; t0 < TT; t0 += DEPTH) {
#pragma unroll
    for (int u = 0; u < DEPTH; ++u) {
      const float4 xa = buf[u][0];
      const float4 xb = buf[u][1];

      // Prefetch step t0+DEPTH+u into this slot (clamped reload at tail —
      // branch-free so the vmcnt pattern stays uniform).
      int tn = t0 + DEPTH + u;
      tn = (tn < TT) ? tn : (TT - 1);
      buf[u][0] = xp[2 * tn];
      buf[u][1] = xp[2 * tn + 1];

      // --- x-projection (independent of the serial chain) ---
      float acc[4];
#pragma unroll
      for (int r4 = 0; r4 < 4; ++r4) {
        float a = bias[r4];
        a = fmaf(wih[r4][0], xa.x, a);
        a = fmaf(wih[r4][1], xa.y, a);
        a = fmaf(wih[r4][2], xa.z, a);
        a = fmaf(wih[r4][3], xa.w, a);
        a = fmaf(wih[r4][4], xb.x, a);
        a = fmaf(wih[r4][5], xb.y, a);
        a = fmaf(wih[r4][6], xb.z, a);
        a = fmaf(wih[r4][7], xb.w, a);
        acc[r4] = a;
      }

      // --- serial chain: broadcast h0..h3 within the quad ---
      const float h0 = dppf<0x00>(h);
      const float h1 = dppf<0x55>(h);
      const float h2 = dppf<0xAA>(h);
      const float h3 = dppf<0xFF>(h);
#pragma unroll
      for (int r4 = 0; r4 < 4; ++r4) {
        float a = acc[r4];
        a = fmaf(whh[r4][0], h0, a);
        a = fmaf(whh[r4][1], h1, a);
        a = fmaf(whh[r4][2], h2, a);
        a = fmaf(whh[r4][3], h3, a);
        acc[r4] = a;
      }

      const float ig = fast_sigmoid(acc[0]);
      const float fg = fast_sigmoid(acc[1]);
      const float gg = fast_tanh(acc[2]);
      const float og = fast_sigmoid(acc[3]);
      c = fmaf(fg, c, ig * gg);
      h = og * fast_tanh(c);
    }
  }

  // --- final FC: out[b] = sum_j h_j * fc_w[j] + fc_b ---
  float v = h * fc_w[j];
  v += dppf<0xB1>(v);  // quad_perm [1,0,3,2]
  v += dppf<0x4E>(v);  // quad_perm [2,3,0,1]
  if (j == 0 && b < B) out[b] = v + fc_b[0];
}

extern "C" void kernel_launch(void* const* d_in, const int* in_sizes, int n_in,
                              void* d_out, int out_size, void* d_ws,
                              size_t ws_size, hipStream_t stream) {
  const float* x = (const float*)d_in[0];
  const float* W_ih = (const float*)d_in[1];
  const float* W_hh = (const float*)d_in[2];
  const float* b_ih = (const float*)d_in[3];
  const float* b_hh = (const float*)d_in[4];
  const float* fc_w = (const float*)d_in[5];
  const float* fc_b = (const float*)d_in[6];
  float* out = (float*)d_out;

  const int B = in_sizes[0] / (TT * II);
  const int nblocks = (B + 15) / 16;
  lstm_fused<<<nblocks, 64, 0, stream>>>(x, W_ih, W_hh, b_ih, b_hh, fc_w, fc_b,
                                         out, B);
}

// Round 3
// 316.818 us; speedup vs baseline: 1.3932x; 1.3042x over previous
//
#include <hip/hip_runtime.h>

// LSTM: B=4096, T=1024, I=8, H=4. fp32.
// Layout: 4 lanes per batch elem (lane j of an aligned quad owns h_j, c_j and
// gate rows {j,4+j,8+j,12+j}). h-broadcast via DPP quad_perm (VALU pipe).
//
// R3: R1/R2 showed ~540 cyc/step memory stall independent of per-wave
// prefetch depth -> the scattered 16-stream quad-broadcast load pattern caps
// per-CU line throughput. Fix: chunked CONTIGUOUS staging. Per 32-step chunk,
// 16x global_load_lds (16B/lane, 1KB contiguous per instr = dense sequential
// lines), double-buffered in two DISTINCT __shared__ arrays (so even a
// conservative vmcnt(0) only waits on ~2500-cyc-old loads). Compute reads
// per-quad float4 from LDS (broadcast; stream rows padded 16B -> 2-way bank
// alias = free). x-proj/hh-proj packed into v_pk_fma_f32 via float2 vectors.

#define TT 1024
#define II 8
#define CHUNK 32
#define NCHUNK (TT / CHUNK)   // 32 chunks, even
#define ROW (CHUNK * II)      // 256 floats of x per stream per chunk
#define SPAD 4                // +16B pad per stream row: breaks bank stride

typedef float v2f __attribute__((ext_vector_type(2)));

template <int CTRL>
__device__ __forceinline__ float dppf(float v) {
  return __int_as_float(
      __builtin_amdgcn_mov_dpp(__float_as_int(v), CTRL, 0xF, 0xF, true));
}

__device__ __forceinline__ float fast_sigmoid(float x) {
  return __builtin_amdgcn_rcpf(1.0f + __expf(-x));
}

__device__ __forceinline__ float fast_tanh(float x) {
  // tanh = 1 - 2/(e^{2x}+1); overflow -> inf -> rcp=0 -> 1 (graceful)
  return 1.0f - 2.0f * __builtin_amdgcn_rcpf(__expf(2.0f * x) + 1.0f);
}

#define GLOAD_LDS16(gp, lp)                                   \
  __builtin_amdgcn_global_load_lds(                           \
      (const __attribute__((address_space(1))) void*)(gp),    \
      (__attribute__((address_space(3))) void*)(lp), 16, 0, 0)

__global__ __launch_bounds__(64, 1) void lstm_fused(
    const float* __restrict__ x, const float* __restrict__ W_ih,
    const float* __restrict__ W_hh, const float* __restrict__ b_ih,
    const float* __restrict__ b_hh, const float* __restrict__ fc_w,
    const float* __restrict__ fc_b, float* __restrict__ out, int B) {
  const int lane = threadIdx.x;  // 0..63
  const int j = lane & 3;
  const int grp = lane >> 2;
  const int b = blockIdx.x * 16 + grp;

  // Two DISTINCT buffers (not one [2][..] array) so LLVM AA separates the
  // DMA->ds_read dependencies across chunks.
  __shared__ float xs0[16][ROW + SPAD];
  __shared__ float xs1[16][ROW + SPAD];

  // Per-lane weights, packed in r4-pairs for v_pk_fma_f32.
  // a01 = (gate i_j, gate f_j) pre-acts; a23 = (g_j, o_j).
  v2f wih01[II], wih23[II], whh01[4], whh23[4];
  v2f bias01, bias23;
#pragma unroll
  for (int k = 0; k < II; ++k) {
    wih01[k] = v2f{W_ih[(0 * 4 + j) * II + k], W_ih[(1 * 4 + j) * II + k]};
    wih23[k] = v2f{W_ih[(2 * 4 + j) * II + k], W_ih[(3 * 4 + j) * II + k]};
  }
#pragma unroll
  for (int k = 0; k < 4; ++k) {
    whh01[k] = v2f{W_hh[(0 * 4 + j) * 4 + k], W_hh[(1 * 4 + j) * 4 + k]};
    whh23[k] = v2f{W_hh[(2 * 4 + j) * 4 + k], W_hh[(3 * 4 + j) * 4 + k]};
  }
  bias01 = v2f{b_ih[0 * 4 + j] + b_hh[0 * 4 + j],
               b_ih[1 * 4 + j] + b_hh[1 * 4 + j]};
  bias23 = v2f{b_ih[2 * 4 + j] + b_hh[2 * 4 + j],
               b_ih[3 * 4 + j] + b_hh[3 * 4 + j]};

  const size_t blockBase = (size_t)blockIdx.x * 16;

  // Issue one chunk's staging: 16 instrs, each 1KB contiguous from stream s.
  auto issue0 = [&](int t0) {
#pragma unroll
    for (int s = 0; s < 16; ++s) {
      const float* gp = x + (blockBase + s) * (TT * II) + t0 * II + lane * 4;
      GLOAD_LDS16(gp, &xs0[s][0]);
    }
  };
  auto issue1 = [&](int t0) {
#pragma unroll
    for (int s = 0; s < 16; ++s) {
      const float* gp = x + (blockBase + s) * (TT * II) + t0 * II + lane * 4;
      GLOAD_LDS16(gp, &xs1[s][0]);
    }
  };

  float h = 0.0f, c = 0.0f;

  auto step = [&](float4 xa, float4 xb) {
    v2f a01 = bias01, a23 = bias23;
#define XFMA(k, val)                                      \
  {                                                       \
    v2f xv = v2f{(val), (val)};                           \
    a01 = __builtin_elementwise_fma(wih01[k], xv, a01);   \
    a23 = __builtin_elementwise_fma(wih23[k], xv, a23);   \
  }
    XFMA(0, xa.x) XFMA(1, xa.y) XFMA(2, xa.z) XFMA(3, xa.w)
    XFMA(4, xb.x) XFMA(5, xb.y) XFMA(6, xb.z) XFMA(7, xb.w)
#undef XFMA
    const float h0 = dppf<0x00>(h);
    const float h1 = dppf<0x55>(h);
    const float h2 = dppf<0xAA>(h);
    const float h3 = dppf<0xFF>(h);
#define HFMA(k, val)                                      \
  {                                                       \
    v2f hv = v2f{(val), (val)};                           \
    a01 = __builtin_elementwise_fma(whh01[k], hv, a01);   \
    a23 = __builtin_elementwise_fma(whh23[k], hv, a23);   \
  }
    HFMA(0, h0) HFMA(1, h1) HFMA(2, h2) HFMA(3, h3)
#undef HFMA
    const float ig = fast_sigmoid(a01.x);
    const float fg = fast_sigmoid(a01.y);
    const float gg = fast_tanh(a23.x);
    const float og = fast_sigmoid(a23.y);
    c = fmaf(fg, c, ig * gg);
    h = og * fast_tanh(c);
  };

  auto compute_chunk = [&](const float (*xs)[ROW + SPAD]) {
    const float* row = &xs[grp][0];
    float4 xa = *(const float4*)(row);
    float4 xb = *(const float4*)(row + 4);
#pragma unroll 4
    for (int u = 0; u < CHUNK; ++u) {
      const int un = (u + 1 < CHUNK) ? (u + 1) : u;  // tail re-read, harmless
      const float4 na = *(const float4*)(row + un * 8);
      const float4 nb = *(const float4*)(row + un * 8 + 4);
      step(xa, xb);
      xa = na;
      xb = nb;
    }
  };

  // Prologue: chunks 0 and 1 in flight.
  issue0(0);
  issue1(CHUNK);

  for (int ck = 0; ck < NCHUNK; ck += 2) {
    compute_chunk(xs0);                                   // chunk ck
    if (ck + 2 < NCHUNK) issue0((ck + 2) * CHUNK);        // refill xs0
    compute_chunk(xs1);                                   // chunk ck+1
    if (ck + 3 < NCHUNK) issue1((ck + 3) * CHUNK);        // refill xs1
  }

  // Final FC: out[b] = sum_j h_j * fc_w[j] + fc_b
  float v = h * fc_w[j];
  v += dppf<0xB1>(v);  // quad_perm [1,0,3,2]
  v += dppf<0x4E>(v);  // quad_perm [2,3,0,1]
  if (j == 0 && b < B) out[b] = v + fc_b[0];
}

extern "C" void kernel_launch(void* const* d_in, const int* in_sizes, int n_in,
                              void* d_out, int out_size, void* d_ws,
                              size_t ws_size, hipStream_t stream) {
  const float* x = (const float*)d_in[0];
  const float* W_ih = (const float*)d_in[1];
  const float* W_hh = (const float*)d_in[2];
  const float* b_ih = (const float*)d_in[3];
  const float* b_hh = (const float*)d_in[4];
  const float* fc_w = (const float*)d_in[5];
  const float* fc_b = (const float*)d_in[6];
  float* out = (float*)d_out;

  const int B = in_sizes[0] / (TT * II);
  const int nblocks = (B + 15) / 16;
  lstm_fused<<<nblocks, 64, 0, stream>>>(x, W_ih, W_hh, b_ih, b_hh, fc_w, fc_b,
                                         out, B);
}

// Round 4
// 260.102 us; speedup vs baseline: 1.6970x; 1.2181x over previous
//
#include <hip/hip_runtime.h>

// LSTM: B=4096, T=1024, I=8, H=4. fp32.
// R4: producer/consumer wave specialization (128-thread block, 2 waves).
//  - wave 0 (producer): global_load_lds x-staging (R3 pattern, contiguous
//    1KB/instr) + input projection preact = bias + W_ih*x_t for 16 streams,
//    written to a double-buffered LDS pre-act ring. All its vmcnt drains and
//    ~60cyc/step of VALU run in the consumer's shadow on another SIMD (m114).
//  - wave 1 (consumer): the serial scan only: ds_read_b128 preact, DPP
//    h-broadcast, 8 pk-fma (W_hh*h), activations, state update.
// Sync: one __syncthreads per 32-step chunk (both waves execute 1+NCHUNK
// barriers). Consumer never touches vmcnt.
// Lane layout (both waves): 4 lanes/batch elem; lane j owns hidden j and
// gate rows {j,4+j,8+j,12+j} (PyTorch i,f,g,o order).

#define TT 1024
#define II 8
#define CHUNK 32
#define NCHUNK (TT / CHUNK)  // 32
#define ROW (CHUNK * II)     // 256 floats x per stream per chunk
#define SPAD 4

typedef float v2f __attribute__((ext_vector_type(2)));

template <int CTRL>
__device__ __forceinline__ float dppf(float v) {
  return __int_as_float(
      __builtin_amdgcn_mov_dpp(__float_as_int(v), CTRL, 0xF, 0xF, true));
}

__device__ __forceinline__ float fast_sigmoid(float x) {
  return __builtin_amdgcn_rcpf(1.0f + __expf(-x));
}

__device__ __forceinline__ float fast_tanh(float x) {
  // tanh = 1 - 2/(e^{2x}+1); overflow -> inf -> rcp=0 -> 1 (graceful)
  return 1.0f - 2.0f * __builtin_amdgcn_rcpf(__expf(2.0f * x) + 1.0f);
}

#define GLOAD_LDS16(gp, lp)                                   \
  __builtin_amdgcn_global_load_lds(                           \
      (const __attribute__((address_space(1))) void*)(gp),    \
      (__attribute__((address_space(3))) void*)(lp), 16, 0, 0)

__global__ __launch_bounds__(128, 1) void lstm_fused(
    const float* __restrict__ x, const float* __restrict__ W_ih,
    const float* __restrict__ W_hh, const float* __restrict__ b_ih,
    const float* __restrict__ b_hh, const float* __restrict__ fc_w,
    const float* __restrict__ fc_b, float* __restrict__ out, int B) {
  const int tid = threadIdx.x;
  const int wave = tid >> 6;
  const int lane = tid & 63;
  const int j = lane & 3;
  const int grp = lane >> 2;
  const int b = blockIdx.x * 16 + grp;

  // x staging (double buffer, distinct objects for AA)
  __shared__ float xs0[16][ROW + SPAD];
  __shared__ float xs1[16][ROW + SPAD];
  // pre-act ring: [step u][stream][hidden j][4 gates] -> lane reads/writes
  // one contiguous float4; wave accesses 1KB stride-1 per step (conflict-free)
  __shared__ float pa0[CHUNK][16][16];
  __shared__ float pa1[CHUNK][16][16];

  if (wave == 0) {
    // ---------------- producer ----------------
    v2f wih01[II], wih23[II];
    v2f bias01, bias23;
#pragma unroll
    for (int k = 0; k < II; ++k) {
      wih01[k] = v2f{W_ih[(0 * 4 + j) * II + k], W_ih[(1 * 4 + j) * II + k]};
      wih23[k] = v2f{W_ih[(2 * 4 + j) * II + k], W_ih[(3 * 4 + j) * II + k]};
    }
    bias01 = v2f{b_ih[0 * 4 + j] + b_hh[0 * 4 + j],
                 b_ih[1 * 4 + j] + b_hh[1 * 4 + j]};
    bias23 = v2f{b_ih[2 * 4 + j] + b_hh[2 * 4 + j],
                 b_ih[3 * 4 + j] + b_hh[3 * 4 + j]};

    const size_t blockBase = (size_t)blockIdx.x * 16;

    auto issue = [&](float(*xs)[ROW + SPAD], int t0) {
#pragma unroll
      for (int s = 0; s < 16; ++s) {
        const float* gp =
            x + (blockBase + s) * (TT * II) + (size_t)t0 * II + lane * 4;
        GLOAD_LDS16(gp, &xs[s][0]);
      }
    };

    auto produce = [&](float(*pa)[16][16], const float(*xs)[ROW + SPAD]) {
      const float* row = &xs[grp][0];
#pragma unroll 8
      for (int u = 0; u < CHUNK; ++u) {
        const float4 xa = *(const float4*)(row + u * 8);
        const float4 xb = *(const float4*)(row + u * 8 + 4);
        v2f a01 = bias01, a23 = bias23;
#define XFMA(k, val)                                    \
  {                                                     \
    v2f xv = v2f{(val), (val)};                         \
    a01 = __builtin_elementwise_fma(wih01[k], xv, a01); \
    a23 = __builtin_elementwise_fma(wih23[k], xv, a23); \
  }
        XFMA(0, xa.x) XFMA(1, xa.y) XFMA(2, xa.z) XFMA(3, xa.w)
        XFMA(4, xb.x) XFMA(5, xb.y) XFMA(6, xb.z) XFMA(7, xb.w)
#undef XFMA
        *(float4*)&pa[u][grp][j * 4] = float4{a01.x, a01.y, a23.x, a23.y};
      }
    };

    // prologue: stage chunks 0,1; produce chunk 0
    issue(xs0, 0);
    issue(xs1, CHUNK);
    produce(pa0, xs0);
    __syncthreads();

    for (int ck = 0; ck < NCHUNK; ++ck) {
      // produce chunk ck+1 FIRST (its x was staged last iteration -> vmcnt
      // drained long ago), then issue staging for chunk ck+2 into the x
      // buffer freed by chunk ck.
      if (ck + 1 < NCHUNK)
        produce(((ck + 1) & 1) ? pa1 : pa0, ((ck + 1) & 1) ? xs1 : xs0);
      if (ck + 2 < NCHUNK) issue((ck & 1) ? xs1 : xs0, (ck + 2) * CHUNK);
      __syncthreads();
    }
  } else {
    // ---------------- consumer (serial scan) ----------------
    v2f whh01[4], whh23[4];
#pragma unroll
    for (int k = 0; k < 4; ++k) {
      whh01[k] = v2f{W_hh[(0 * 4 + j) * 4 + k], W_hh[(1 * 4 + j) * 4 + k]};
      whh23[k] = v2f{W_hh[(2 * 4 + j) * 4 + k], W_hh[(3 * 4 + j) * 4 + k]};
    }
    float h = 0.0f, c = 0.0f;

    __syncthreads();

    for (int ck = 0; ck < NCHUNK; ++ck) {
      const float(*pa)[16][16] = (ck & 1) ? pa1 : pa0;
      const float* base = &pa[0][grp][j * 4];
      float4 g = *(const float4*)base;
#pragma unroll 8
      for (int u = 0; u < CHUNK; ++u) {
        const int un = (u + 1 < CHUNK) ? (u + 1) : u;  // clamp tail
        const float4 gn = *(const float4*)(base + un * 256);

        v2f a01 = v2f{g.x, g.y};
        v2f a23 = v2f{g.z, g.w};
        const float h0 = dppf<0x00>(h);
        const float h1 = dppf<0x55>(h);
        const float h2 = dppf<0xAA>(h);
        const float h3 = dppf<0xFF>(h);
#define HFMA(k, val)                                    \
  {                                                     \
    v2f hv = v2f{(val), (val)};                         \
    a01 = __builtin_elementwise_fma(whh01[k], hv, a01); \
    a23 = __builtin_elementwise_fma(whh23[k], hv, a23); \
  }
        HFMA(0, h0) HFMA(1, h1) HFMA(2, h2) HFMA(3, h3)
#undef HFMA
        const float ig = fast_sigmoid(a01.x);
        const float fg = fast_sigmoid(a01.y);
        const float gg = fast_tanh(a23.x);
        const float og = fast_sigmoid(a23.y);
        c = fmaf(fg, c, ig * gg);
        h = og * fast_tanh(c);

        g = gn;
      }
      __syncthreads();
    }

    // final FC: out[b] = sum_j h_j * fc_w[j] + fc_b
    float v = h * fc_w[j];
    v += dppf<0xB1>(v);  // quad_perm [1,0,3,2]
    v += dppf<0x4E>(v);  // quad_perm [2,3,0,1]
    if (j == 0 && b < B) out[b] = v + fc_b[0];
  }
}

extern "C" void kernel_launch(void* const* d_in, const int* in_sizes, int n_in,
                              void* d_out, int out_size, void* d_ws,
                              size_t ws_size, hipStream_t stream) {
  const float* x = (const float*)d_in[0];
  const float* W_ih = (const float*)d_in[1];
  const float* W_hh = (const float*)d_in[2];
  const float* b_ih = (const float*)d_in[3];
  const float* b_hh = (const float*)d_in[4];
  const float* fc_w = (const float*)d_in[5];
  const float* fc_b = (const float*)d_in[6];
  float* out = (float*)d_out;

  const int B = in_sizes[0] / (TT * II);
  const int nblocks = (B + 15) / 16;
  lstm_fused<<<nblocks, 128, 0, stream>>>(x, W_ih, W_hh, b_ih, b_hh, fc_w,
                                          fc_b, out, B);
}

// Round 5
// 259.758 us; speedup vs baseline: 1.6993x; 1.0013x over previous
//
#include <hip/hip_runtime.h>

// LSTM: B=4096, T=1024, I=8, H=4. fp32.
// R5 structure: producer/consumer wave split (128 threads).
//  - wave 0 (producer): global_load_lds x staging (contiguous 1KB/instr) +
//    input projection -> double-buffered LDS pre-act ring. Pre-acts are
//    emitted PRE-SCALED for exp2-domain activations.
//  - wave 1 (consumer): serial scan. R5 changes vs R4:
//    (1) register-batched pre-act reads: 8x ds_read_b128 ping-pong batches
//        -> no per-step LDS round-trip on the chain (R4 lost ~120cyc/step
//        to a conservative lgkmcnt(0) covering the just-issued prefetch).
//    (2) exp2-domain gates: rows i,f,o scaled by -log2e, row g by +2log2e,
//        c carried as c' = 2log2e*c. sig/tanh = rcp(1+exp2(z)) directly:
//        kills 5 v_mul on the chain + tanh rescale.
// Lane layout: 4 lanes/batch elem; lane j owns hidden j, gate rows
// {j,4+j,8+j,12+j} (PyTorch i,f,g,o). h-broadcast via DPP quad_perm.

#define TT 1024
#define II 8
#define CHUNK 32
#define NCHUNK (TT / CHUNK)  // 32
#define ROW (CHUNK * II)     // 256 floats x per stream per chunk
#define SPAD 4

#define L2E 1.4426950408889634f
#define SIG_SCALE (-L2E)       // i,f,o rows
#define G_SCALE (2.0f * L2E)   // g row

typedef float v2f __attribute__((ext_vector_type(2)));

template <int CTRL>
__device__ __forceinline__ float dppf(float v) {
  return __int_as_float(
      __builtin_amdgcn_mov_dpp(__float_as_int(v), CTRL, 0xF, 0xF, true));
}

__device__ __forceinline__ float ex2(float x) {
  return __builtin_amdgcn_exp2f(x);
}
__device__ __forceinline__ float rcp(float x) {
  return __builtin_amdgcn_rcpf(x);
}

#define GLOAD_LDS16(gp, lp)                                   \
  __builtin_amdgcn_global_load_lds(                           \
      (const __attribute__((address_space(1))) void*)(gp),    \
      (__attribute__((address_space(3))) void*)(lp), 16, 0, 0)

__global__ __launch_bounds__(128, 1) void lstm_fused(
    const float* __restrict__ x, const float* __restrict__ W_ih,
    const float* __restrict__ W_hh, const float* __restrict__ b_ih,
    const float* __restrict__ b_hh, const float* __restrict__ fc_w,
    const float* __restrict__ fc_b, float* __restrict__ out, int B) {
  const int tid = threadIdx.x;
  const int wave = tid >> 6;
  const int lane = tid & 63;
  const int j = lane & 3;
  const int grp = lane >> 2;
  const int b = blockIdx.x * 16 + grp;

  __shared__ float xs0[16][ROW + SPAD];
  __shared__ float xs1[16][ROW + SPAD];
  // pre-act ring: [step][stream][j*4 + gate] — lane rw one contiguous float4;
  // wave touches 1KB stride-1 per step (2-way bank alias = free).
  __shared__ float pa0[CHUNK][16][16];
  __shared__ float pa1[CHUNK][16][16];

  if (wave == 0) {
    // ---------------- producer ----------------
    v2f wih01[II], wih23[II];
    v2f bias01, bias23;
#pragma unroll
    for (int k = 0; k < II; ++k) {
      wih01[k] = v2f{SIG_SCALE * W_ih[(0 * 4 + j) * II + k],
                     SIG_SCALE * W_ih[(1 * 4 + j) * II + k]};
      wih23[k] = v2f{G_SCALE * W_ih[(2 * 4 + j) * II + k],
                     SIG_SCALE * W_ih[(3 * 4 + j) * II + k]};
    }
    bias01 = v2f{SIG_SCALE * (b_ih[0 * 4 + j] + b_hh[0 * 4 + j]),
                 SIG_SCALE * (b_ih[1 * 4 + j] + b_hh[1 * 4 + j])};
    bias23 = v2f{G_SCALE * (b_ih[2 * 4 + j] + b_hh[2 * 4 + j]),
                 SIG_SCALE * (b_ih[3 * 4 + j] + b_hh[3 * 4 + j])};

    const size_t blockBase = (size_t)blockIdx.x * 16;

    auto issue = [&](float(*xs)[ROW + SPAD], int t0) {
#pragma unroll
      for (int s = 0; s < 16; ++s) {
        const float* gp =
            x + (blockBase + s) * (TT * II) + (size_t)t0 * II + lane * 4;
        GLOAD_LDS16(gp, &xs[s][0]);
      }
    };

    auto produce = [&](float(*pa)[16][16], const float(*xs)[ROW + SPAD]) {
      const float* row = &xs[grp][0];
#pragma unroll 8
      for (int u = 0; u < CHUNK; ++u) {
        const float4 xa = *(const float4*)(row + u * 8);
        const float4 xb = *(const float4*)(row + u * 8 + 4);
        v2f a01 = bias01, a23 = bias23;
#define XFMA(k, val)                                    \
  {                                                     \
    v2f xv = v2f{(val), (val)};                         \
    a01 = __builtin_elementwise_fma(wih01[k], xv, a01); \
    a23 = __builtin_elementwise_fma(wih23[k], xv, a23); \
  }
        XFMA(0, xa.x) XFMA(1, xa.y) XFMA(2, xa.z) XFMA(3, xa.w)
        XFMA(4, xb.x) XFMA(5, xb.y) XFMA(6, xb.z) XFMA(7, xb.w)
#undef XFMA
        *(float4*)&pa[u][grp][j * 4] = float4{a01.x, a01.y, a23.x, a23.y};
      }
    };

    issue(xs0, 0);
    issue(xs1, CHUNK);
    produce(pa0, xs0);
    __syncthreads();

    for (int ck = 0; ck < NCHUNK; ++ck) {
      if (ck + 1 < NCHUNK)
        produce(((ck + 1) & 1) ? pa1 : pa0, ((ck + 1) & 1) ? xs1 : xs0);
      if (ck + 2 < NCHUNK) issue((ck & 1) ? xs1 : xs0, (ck + 2) * CHUNK);
      __syncthreads();
    }
  } else {
    // ---------------- consumer (serial scan) ----------------
    // W_hh rows pre-scaled to match the producer's pre-act domain.
    v2f whh01[4], whh23[4];
#pragma unroll
    for (int k = 0; k < 4; ++k) {
      whh01[k] = v2f{SIG_SCALE * W_hh[(0 * 4 + j) * 4 + k],
                     SIG_SCALE * W_hh[(1 * 4 + j) * 4 + k]};
      whh23[k] = v2f{G_SCALE * W_hh[(2 * 4 + j) * 4 + k],
                     SIG_SCALE * W_hh[(3 * 4 + j) * 4 + k]};
    }
    float h = 0.0f, c2 = 0.0f;  // c2 = 2*log2e * c

    auto step = [&](float4 g) {
      const float h0 = dppf<0x00>(h);
      const float h1 = dppf<0x55>(h);
      const float h2 = dppf<0xAA>(h);
      const float h3 = dppf<0xFF>(h);
      v2f a01 = v2f{g.x, g.y};
      v2f a23 = v2f{g.z, g.w};
#define HFMA(k, val)                                    \
  {                                                     \
    v2f hv = v2f{(val), (val)};                         \
    a01 = __builtin_elementwise_fma(whh01[k], hv, a01); \
    a23 = __builtin_elementwise_fma(whh23[k], hv, a23); \
  }
      HFMA(0, h0) HFMA(1, h1) HFMA(2, h2) HFMA(3, h3)
#undef HFMA
      // a01 = {i', f'} (scaled -log2e), a23 = {g' (2log2e), o' (-log2e)}
      const float ig = rcp(1.0f + ex2(a01.x));  // sig(i)
      const float fg = rcp(1.0f + ex2(a01.y));  // sig(f)
      const float rg = rcp(1.0f + ex2(a23.x));  // (1-tanh(g))/2
      const float og = rcp(1.0f + ex2(a23.y));  // sig(o)
      const float gg2 = fmaf(rg, -2.0f * G_SCALE, G_SCALE);  // 2log2e*tanh(g)
      c2 = fmaf(fg, c2, ig * gg2);
      const float rc = rcp(1.0f + ex2(c2));  // (1-tanh(c))/2
      const float m2og = -2.0f * og;         // off-chain
      h = fmaf(rc, m2og, og);                // og*tanh(c)
    };

    __syncthreads();

    for (int ck = 0; ck < NCHUNK; ++ck) {
      const float(*pa)[16][16] = (ck & 1) ? pa1 : pa0;
      const float* base = &pa[0][grp][j * 4];

      float4 ra[8], rb[8];
#define LOADB(r, u0)                                                \
  {                                                                 \
    _Pragma("unroll") for (int k = 0; k < 8; ++k) (r)[k] =          \
        *(const float4*)(base + (u0 + k) * 256);                    \
  }
#define COMP8(r)                                   \
  { _Pragma("unroll") for (int k = 0; k < 8; ++k) step((r)[k]); }

      LOADB(ra, 0)
      LOADB(rb, 8)
      COMP8(ra)
      LOADB(ra, 16)
      COMP8(rb)
      LOADB(rb, 24)
      COMP8(ra)
      COMP8(rb)
#undef LOADB
#undef COMP8
      __syncthreads();
    }

    // final FC: out[b] = sum_j h_j * fc_w[j] + fc_b
    float v = h * fc_w[j];
    v += dppf<0xB1>(v);  // quad_perm [1,0,3,2]
    v += dppf<0x4E>(v);  // quad_perm [2,3,0,1]
    if (j == 0 && b < B) out[b] = v + fc_b[0];
  }
}

extern "C" void kernel_launch(void* const* d_in, const int* in_sizes, int n_in,
                              void* d_out, int out_size, void* d_ws,
                              size_t ws_size, hipStream_t stream) {
  const float* x = (const float*)d_in[0];
  const float* W_ih = (const float*)d_in[1];
  const float* W_hh = (const float*)d_in[2];
  const float* b_ih = (const float*)d_in[3];
  const float* b_hh = (const float*)d_in[4];
  const float* fc_w = (const float*)d_in[5];
  const float* fc_b = (const float*)d_in[6];
  float* out = (float*)d_out;

  const int B = in_sizes[0] / (TT * II);
  const int nblocks = (B + 15) / 16;
  lstm_fused<<<nblocks, 128, 0, stream>>>(x, W_ih, W_hh, b_ih, b_hh, fc_w,
                                          fc_b, out, B);
}